// Round 1
// baseline (287.775 us; speedup 1.0000x reference)
//
#include <hip/hip_runtime.h>
#include <hip/hip_bf16.h>
#include <stdint.h>

#define P_B 4096
#define P_N 16384
#define P_F 768
#define P_E 512

typedef __attribute__((ext_vector_type(8))) __bf16 bf16x8;
typedef __attribute__((ext_vector_type(4))) float f32x4;

__device__ __forceinline__ unsigned short bfbits(float x) {
    __bf16 h = (__bf16)x;
    union { __bf16 h; unsigned short u; } cv;
    cv.h = h;
    return cv.u;
}
__device__ __forceinline__ float bf2f(unsigned short u) {
    union { float f; unsigned int i; } cv;
    cv.i = ((unsigned int)u) << 16;
    return cv.f;
}

// ---------------------------------------------------------------------------
// Embed: C[row][col] = src[row]·g_w[col] + g_b[col], stored bf16.
// Combined rows: 0..4095 from X, 4096..20479 from D. Also accumulates
// per-row sum of squares (of the bf16-rounded values) into norm2[].
// 128x128 tile, 256 threads (4 waves, 2x2), 16x16x32 bf16 MFMA, BK=32.
// fp32 -> bf16 convert-on-stage (inputs are fp32 in global).
// ---------------------------------------------------------------------------
__global__ __launch_bounds__(256, 2) void embed_kernel(
    const float* __restrict__ X, const float* __restrict__ D,
    const float* __restrict__ gw, const float* __restrict__ gb,
    unsigned short* __restrict__ emb, float* __restrict__ norm2)
{
    __shared__ unsigned short As[128 * 32];
    __shared__ unsigned short Bs[128 * 32];
    const int tid = threadIdx.x;
    const int lane = tid & 63;
    const int wave = tid >> 6;
    const int q = lane >> 4, c = lane & 15;
    const int wrow = (wave >> 1) * 64;
    const int wcol = (wave & 1) * 64;
    const int colTile = blockIdx.x;   // 0..3   (E tiles)
    const int rowTile = blockIdx.y;   // 0..159 (combined row tiles)

    const float* srcA;
    int srcRow0;
    if (rowTile < 32) { srcA = X; srcRow0 = rowTile * 128; }
    else              { srcA = D; srcRow0 = (rowTile - 32) * 128; }
    const int rowG0 = rowTile * 128;
    const int col0 = colTile * 128;

    f32x4 acc[4][4];
    const f32x4 zero = {0.f, 0.f, 0.f, 0.f};
#pragma unroll
    for (int i = 0; i < 4; i++)
#pragma unroll
        for (int j = 0; j < 4; j++) acc[i][j] = zero;

    for (int kt = 0; kt < P_F / 32; ++kt) {
        const int k0 = kt * 32;
        __syncthreads();
#pragma unroll
        for (int l = 0; l < 4; l++) {
            const int idx = l * 256 + tid;     // 0..1023
            const int row = idx >> 3;          // 0..127
            const int ch = idx & 7;            // 4-float chunk
            const float4 va = *(const float4*)(srcA + (size_t)(srcRow0 + row) * P_F + k0 + ch * 4);
            ushort4 ha;
            ha.x = bfbits(va.x); ha.y = bfbits(va.y); ha.z = bfbits(va.z); ha.w = bfbits(va.w);
            *(ushort4*)(&As[row * 32 + ch * 4]) = ha;
            const float4 vb = *(const float4*)(gw + (size_t)(col0 + row) * P_F + k0 + ch * 4);
            ushort4 hb;
            hb.x = bfbits(vb.x); hb.y = bfbits(vb.y); hb.z = bfbits(vb.z); hb.w = bfbits(vb.w);
            *(ushort4*)(&Bs[row * 32 + ch * 4]) = hb;
        }
        __syncthreads();
        bf16x8 af[4], bfr[4];
#pragma unroll
        for (int i = 0; i < 4; i++)
            af[i] = *(const bf16x8*)(&As[(wrow + i * 16 + c) * 32 + q * 8]);
#pragma unroll
        for (int j = 0; j < 4; j++)
            bfr[j] = *(const bf16x8*)(&Bs[(wcol + j * 16 + c) * 32 + q * 8]);
#pragma unroll
        for (int i = 0; i < 4; i++)
#pragma unroll
            for (int j = 0; j < 4; j++)
                acc[i][j] = __builtin_amdgcn_mfma_f32_16x16x32_bf16(af[i], bfr[j], acc[i][j], 0, 0, 0);
    }

    // epilogue: bias add, bf16 store, row-wise sum of squares
    float ss[4][4];
#pragma unroll
    for (int i = 0; i < 4; i++)
#pragma unroll
        for (int r = 0; r < 4; r++) ss[i][r] = 0.f;
#pragma unroll
    for (int j = 0; j < 4; j++) {
        const int colg = col0 + wcol + j * 16 + c;
        const float bias = gb[colg];
#pragma unroll
        for (int i = 0; i < 4; i++) {
#pragma unroll
            for (int r = 0; r < 4; r++) {
                const int rowg = rowG0 + wrow + i * 16 + q * 4 + r;
                const float v = acc[i][j][r] + bias;
                const unsigned short hb = bfbits(v);
                emb[(size_t)rowg * P_E + colg] = hb;
                const float vs = bf2f(hb);
                ss[i][r] = fmaf(vs, vs, ss[i][r]);
            }
        }
    }
#pragma unroll
    for (int i = 0; i < 4; i++)
#pragma unroll
        for (int r = 0; r < 4; r++) {
            float s = ss[i][r];
            s += __shfl_xor(s, 1);
            s += __shfl_xor(s, 2);
            s += __shfl_xor(s, 4);
            s += __shfl_xor(s, 8);
            ss[i][r] = s;
        }
    if (c == 0) {
#pragma unroll
        for (int i = 0; i < 4; i++)
#pragma unroll
            for (int r = 0; r < 4; r++) {
                const int rowg = rowG0 + wrow + i * 16 + q * 4 + r;
                atomicAdd(&norm2[rowg], ss[i][r]);
            }
    }
}

// ---------------------------------------------------------------------------
// Finalize: norm2[i] -> inv_norm^3 (X rows), inv_norm^3 * (2r-1) (D rows)
// ---------------------------------------------------------------------------
__global__ void finalize_kernel(float* __restrict__ nf, const float* __restrict__ r)
{
    const int i = blockIdx.x * 256 + threadIdx.x;
    if (i >= P_B + P_N) return;
    float nrm = sqrtf(nf[i]);
    nrm = fmaxf(nrm, 1e-12f);
    const float inv = 1.0f / nrm;
    float w = inv * inv * inv;
    if (i >= P_B) {
        const float rv = r[i - P_B];
        w *= (2.0f * rv - 1.0f);
    }
    nf[i] = w;
}

// ---------------------------------------------------------------------------
// Echo: for tile (btile, ntile): dot = Xe_tile @ De_tile^T (K=512, bf16 MFMA),
// echo[b] += inx3[b] * sum_n dot^3 * (ind3*r2)[n].
// m97 structure: global_load_lds width-16 staging, 128x128, BK=32.
// ---------------------------------------------------------------------------
__global__ __launch_bounds__(256, 2) void echo_kernel(
    const unsigned short* __restrict__ emb, const float* __restrict__ fbuf,
    float* __restrict__ echo)
{
    __shared__ unsigned short As[128 * 32];
    __shared__ unsigned short Bs[128 * 32];
    const int tid = threadIdx.x;
    const int lane = tid & 63;
    const int wave = tid >> 6;
    const int q = lane >> 4, c = lane & 15;
    const int wrow = (wave >> 1) * 64;
    const int wcol = (wave & 1) * 64;
    const int ntile = blockIdx.x;  // 0..127
    const int btile = blockIdx.y;  // 0..31
    const unsigned short* Ag = emb;                        // Xe rows
    const unsigned short* Bg = emb + (size_t)P_B * P_E;    // De rows
    const int row0 = btile * 128;
    const int col0 = ntile * 128;

    f32x4 acc[4][4];
    const f32x4 zero = {0.f, 0.f, 0.f, 0.f};
#pragma unroll
    for (int i = 0; i < 4; i++)
#pragma unroll
        for (int j = 0; j < 4; j++) acc[i][j] = zero;

    for (int kt = 0; kt < P_E / 32; ++kt) {
        const int k0 = kt * 32;
        __syncthreads();
#pragma unroll
        for (int l = 0; l < 2; l++) {
            const int idx = l * 256 + tid;   // 0..511
            const int row = idx >> 2;        // 0..127
            const int ch = idx & 3;          // 16B chunk within the 64B row
            __builtin_amdgcn_global_load_lds(
                (const __attribute__((address_space(1))) unsigned int*)(Ag + (size_t)(row0 + row) * P_E + k0 + ch * 8),
                (__attribute__((address_space(3))) unsigned int*)(&As[l * 2048 + wave * 512]),
                16, 0, 0);
            __builtin_amdgcn_global_load_lds(
                (const __attribute__((address_space(1))) unsigned int*)(Bg + (size_t)(col0 + row) * P_E + k0 + ch * 8),
                (__attribute__((address_space(3))) unsigned int*)(&Bs[l * 2048 + wave * 512]),
                16, 0, 0);
        }
        __syncthreads();
        bf16x8 af[4], bfr[4];
#pragma unroll
        for (int i = 0; i < 4; i++)
            af[i] = *(const bf16x8*)(&As[(wrow + i * 16 + c) * 32 + q * 8]);
#pragma unroll
        for (int j = 0; j < 4; j++)
            bfr[j] = *(const bf16x8*)(&Bs[(wcol + j * 16 + c) * 32 + q * 8]);
#pragma unroll
        for (int i = 0; i < 4; i++)
#pragma unroll
            for (int j = 0; j < 4; j++)
                acc[i][j] = __builtin_amdgcn_mfma_f32_16x16x32_bf16(af[i], bfr[j], acc[i][j], 0, 0, 0);
    }

    // epilogue: cube, weight by (ind^3*r2), reduce over columns, atomicAdd rows
    const float* fX = fbuf;
    const float* fD = fbuf + P_B;
    float wc[4];
#pragma unroll
    for (int j = 0; j < 4; j++) wc[j] = fD[col0 + wcol + j * 16 + c];
    float p[4][4];
#pragma unroll
    for (int i = 0; i < 4; i++)
#pragma unroll
        for (int r = 0; r < 4; r++) p[i][r] = 0.f;
#pragma unroll
    for (int i = 0; i < 4; i++)
#pragma unroll
        for (int j = 0; j < 4; j++)
#pragma unroll
            for (int r = 0; r < 4; r++) {
                const float v = acc[i][j][r];
                const float v3 = v * v * v;
                p[i][r] = fmaf(v3, wc[j], p[i][r]);
            }
#pragma unroll
    for (int i = 0; i < 4; i++)
#pragma unroll
        for (int r = 0; r < 4; r++) {
            float s = p[i][r];
            s += __shfl_xor(s, 1);
            s += __shfl_xor(s, 2);
            s += __shfl_xor(s, 4);
            s += __shfl_xor(s, 8);
            p[i][r] = s;
        }
    if (c == 0) {
#pragma unroll
        for (int i = 0; i < 4; i++)
#pragma unroll
            for (int r = 0; r < 4; r++) {
                const int rowg = row0 + wrow + i * 16 + q * 4 + r;
                atomicAdd(&echo[rowg], p[i][r] * fX[rowg]);
            }
    }
}

// ---------------------------------------------------------------------------
// Head: logits = echo*h_w + h_b ; preds = sigmoid(logits)
// ---------------------------------------------------------------------------
__global__ void head_kernel(const float* __restrict__ echo, const float* __restrict__ hw,
                            const float* __restrict__ hb, float* __restrict__ out)
{
    const int i = blockIdx.x * 256 + threadIdx.x;
    if (i >= P_B) return;
    const float logit = fmaf(echo[i], hw[0], hb[0]);
    out[i] = logit;
    out[P_B + i] = 1.0f / (1.0f + expf(-logit));
}

extern "C" void kernel_launch(void* const* d_in, const int* in_sizes, int n_in,
                              void* d_out, int out_size, void* d_ws, size_t ws_size,
                              hipStream_t stream)
{
    const float* X  = (const float*)d_in[0];
    const float* D  = (const float*)d_in[1];
    const float* r  = (const float*)d_in[2];
    const float* gw = (const float*)d_in[3];
    const float* gb = (const float*)d_in[4];
    const float* hw = (const float*)d_in[5];
    const float* hb = (const float*)d_in[6];
    float* out = (float*)d_out;

    char* ws = (char*)d_ws;
    // layout: emb bf16 [20480][512] | norm2/f [20480] f32 | echo [4096] f32
    unsigned short* emb = (unsigned short*)ws;
    const size_t emb_bytes = (size_t)(P_B + P_N) * P_E * sizeof(unsigned short);
    float* norm2 = (float*)(ws + emb_bytes);
    float* echo = norm2 + (P_B + P_N);

    // zero norm2 + echo (contiguous)
    hipMemsetAsync(norm2, 0, (size_t)(P_B + P_N + P_B) * sizeof(float), stream);

    embed_kernel<<<dim3(4, 160), 256, 0, stream>>>(X, D, gw, gb, emb, norm2);
    finalize_kernel<<<dim3((P_B + P_N + 255) / 256), 256, 0, stream>>>(norm2, r);
    echo_kernel<<<dim3(128, 32), 256, 0, stream>>>(emb, norm2, echo);
    head_kernel<<<dim3((P_B + 255) / 256), 256, 0, stream>>>(echo, hw, hb, out);
}